// Round 1
// baseline (999.493 us; speedup 1.0000x reference)
//
#include <hip/hip_runtime.h>

typedef unsigned short u16;
typedef __attribute__((ext_vector_type(8))) short bf16x8;   // MFMA A/B operand (8 bf16 = 4 VGPR)
typedef __attribute__((ext_vector_type(8))) unsigned short u16x8;
typedef __attribute__((ext_vector_type(4))) float f32x4;    // MFMA C/D operand

#define HIDDEN 4096
#define NH 32
#define NKV 8
#define HD 128
#define BB 2
#define SS 2048
#define TOK (BB * SS)   // 4096
#define MAXPOS 4096

__device__ __forceinline__ u16 f2bf(float f) {
  unsigned u = __float_as_uint(f);
  u += 0x7FFFu + ((u >> 16) & 1u);   // RNE
  return (u16)(u >> 16);
}
__device__ __forceinline__ float bf2f(u16 u) {
  return __uint_as_float(((unsigned)u) << 16);
}

__device__ __forceinline__ void gload_lds16(const u16* g, u16* l) {
  __builtin_amdgcn_global_load_lds(
      (const __attribute__((address_space(1))) unsigned int*)g,
      (__attribute__((address_space(3))) unsigned int*)l, 16, 0, 0);
}

// ---------------- conversion kernels ----------------

__global__ void conv_bf16(const float* __restrict__ X, u16* __restrict__ Y, int n8) {
  int i = blockIdx.x * 256 + threadIdx.x;
  if (i >= n8) return;
  const float4* p = (const float4*)X;
  float4 a = p[2 * (long)i], b = p[2 * (long)i + 1];
  u16x8 o;
  o[0] = f2bf(a.x); o[1] = f2bf(a.y); o[2] = f2bf(a.z); o[3] = f2bf(a.w);
  o[4] = f2bf(b.x); o[5] = f2bf(b.y); o[6] = f2bf(b.z); o[7] = f2bf(b.w);
  *(u16x8*)&Y[(long)i * 8] = o;
}

// W [K][N] fp32  ->  Wt [N][K] bf16
__global__ __launch_bounds__(256) void conv_transpose(const float* __restrict__ W,
                                                      u16* __restrict__ Wt,
                                                      int K, int N) {
  __shared__ float tile[64][65];
  const int n0 = blockIdx.x * 64, k0 = blockIdx.y * 64;
  const int t = threadIdx.x;
  const int r = t >> 4, c4 = (t & 15) * 4;
#pragma unroll
  for (int i = 0; i < 4; i++) {
    float4 v = *(const float4*)&W[(long)(k0 + r + i * 16) * N + n0 + c4];
    tile[r + i * 16][c4 + 0] = v.x;
    tile[r + i * 16][c4 + 1] = v.y;
    tile[r + i * 16][c4 + 2] = v.z;
    tile[r + i * 16][c4 + 3] = v.w;
  }
  __syncthreads();
#pragma unroll
  for (int i = 0; i < 4; i++) {
    int n = r + i * 16;
    ushort4 o;
    o.x = f2bf(tile[c4 + 0][n]);
    o.y = f2bf(tile[c4 + 1][n]);
    o.z = f2bf(tile[c4 + 2][n]);
    o.w = f2bf(tile[c4 + 3][n]);
    *(ushort4*)&Wt[(long)(n0 + n) * K + k0 + c4] = o;
  }
}

// ---------------- RoPE ----------------

__global__ void rope_table(float* __restrict__ st, float* __restrict__ ct) {
  int i = blockIdx.x * 256 + threadIdx.x;   // MAXPOS*64
  int pos = i >> 6, j = i & 63;
  // inv_freq = 10000^(-2j/128) = 2^(-2j/128 * log2(10000))
  float inv = exp2f(-(float)(2 * j) * (13.287712379549449f / 128.f));
  float a = (float)pos * inv;
  st[i] = sinf(a);
  ct[i] = cosf(a);
}

__global__ void rope_apply(u16* __restrict__ T, const int* __restrict__ pid,
                           const float* __restrict__ st, const float* __restrict__ ct,
                           int nh, int total) {
  int i = blockIdx.x * 256 + threadIdx.x;
  if (i >= total) return;
  int j = i & 63;
  int rest = i >> 6;
  int h = rest % nh;
  int tok = rest / nh;
  int pos = pid[tok];
  long base = ((long)tok * nh + h) * 128;
  float c = ct[pos * 64 + j], s = st[pos * 64 + j];
  float a = bf2f(T[base + j]), b = bf2f(T[base + 64 + j]);
  T[base + j]      = f2bf(a * c - b * s);
  T[base + 64 + j] = f2bf(b * c + a * s);
}

// V [B,S,NKV,HD] -> Vt [B,NKV,HD,S]
__global__ __launch_bounds__(256) void vtrans(const u16* __restrict__ V, u16* __restrict__ Vt) {
  __shared__ u16 tile[64][68];
  const int s0 = blockIdx.x * 64, d0 = blockIdx.y * 64;
  const int bk = blockIdx.z;            // b*NKV + kvh
  const int b = bk >> 3, kvh = bk & 7;
  const int t = threadIdx.x;
  const int r = t >> 4, c4 = (t & 15) * 4;
#pragma unroll
  for (int i = 0; i < 4; i++) {
    int s = s0 + r + i * 16;
    ushort4 v = *(const ushort4*)&V[(((long)b * SS + s) * NKV + kvh) * HD + d0 + c4];
    tile[r + i * 16][c4 + 0] = v.x;
    tile[r + i * 16][c4 + 1] = v.y;
    tile[r + i * 16][c4 + 2] = v.z;
    tile[r + i * 16][c4 + 3] = v.w;
  }
  __syncthreads();
#pragma unroll
  for (int i = 0; i < 4; i++) {
    int d = r + i * 16;
    ushort4 o;
    o.x = tile[c4 + 0][d];
    o.y = tile[c4 + 1][d];
    o.z = tile[c4 + 2][d];
    o.w = tile[c4 + 3][d];
    *(ushort4*)&Vt[(((long)bk) * HD + d0 + d) * SS + s0 + c4] = o;
  }
}

// ---------------- GEMM: C[M,N] = A[M,K] * B[K,N],  Bt given as [N][K] (bf16) ----------------
// m97-style: 128x128 tile, BK=64, 4 waves (2x2), global_load_lds width-16.

template <typename OT>
__global__ __launch_bounds__(256) void gemm_bt(const u16* __restrict__ A,
                                               const u16* __restrict__ Bt,
                                               OT* __restrict__ C,
                                               int M, int N, int K) {
  __shared__ u16 As[128 * 64];
  __shared__ u16 Bs[128 * 64];
  const int t = threadIdx.x;
  const int lane = t & 63, wv = t >> 6;
  const int wr = wv >> 1, wc = wv & 1;
  const int fr = lane & 15, fq = lane >> 4;
  const long brow = (long)blockIdx.y * 128, bcol = (long)blockIdx.x * 128;

  f32x4 acc[4][4] = {};

  const int rs = wv * 8 + (lane >> 3);   // staging row within 32-row slab
  const int cs = (lane & 7) * 8;         // staging col (elements)
  const u16* Ag = A + (brow + rs) * (long)K + cs;
  const u16* Bg = Bt + (bcol + rs) * (long)K + cs;
  u16* Al = &As[rs * 64 + cs];
  u16* Bl = &Bs[rs * 64 + cs];

  for (int k0 = 0; k0 < K; k0 += 64) {
#pragma unroll
    for (int i = 0; i < 4; i++) {
      gload_lds16(Ag + (long)i * 32 * K + k0, Al + i * 32 * 64);
      gload_lds16(Bg + (long)i * 32 * K + k0, Bl + i * 32 * 64);
    }
    __syncthreads();
#pragma unroll
    for (int kk = 0; kk < 2; kk++) {
      bf16x8 af[4], bfr[4];
#pragma unroll
      for (int m = 0; m < 4; m++)
        af[m] = *(const bf16x8*)&As[(wr * 64 + m * 16 + fr) * 64 + kk * 32 + fq * 8];
#pragma unroll
      for (int n = 0; n < 4; n++)
        bfr[n] = *(const bf16x8*)&Bs[(wc * 64 + n * 16 + fr) * 64 + kk * 32 + fq * 8];
#pragma unroll
      for (int m = 0; m < 4; m++)
#pragma unroll
        for (int n = 0; n < 4; n++)
          acc[m][n] = __builtin_amdgcn_mfma_f32_16x16x32_bf16(af[m], bfr[n], acc[m][n], 0, 0, 0);
    }
    __syncthreads();
  }

#pragma unroll
  for (int m = 0; m < 4; m++)
#pragma unroll
    for (int j = 0; j < 4; j++) {
      long row = brow + wr * 64 + m * 16 + fq * 4 + j;
#pragma unroll
      for (int n = 0; n < 4; n++) {
        long col = bcol + wc * 64 + n * 16 + fr;
        float v = acc[m][n][j];
        if constexpr (sizeof(OT) == 2)
          C[row * N + col] = (OT)f2bf(v);
        else
          C[row * N + col] = v;
      }
    }
}

// ---------------- flash attention (causal, GQA) ----------------
// grid (S/64, NH, B), 256 threads = 4 waves, each wave owns 16 q-rows.
// Q,K: [B,S,H,128] bf16 (rope'd); Vt: [B,NKV,128,S] bf16; O: [B,S,NH,128] bf16.

__global__ __launch_bounds__(256) void attn_fwd(const u16* __restrict__ Q,
                                                const u16* __restrict__ K,
                                                const u16* __restrict__ Vt,
                                                const float* __restrict__ amask,
                                                u16* __restrict__ O) {
  const int b = blockIdx.z, h = blockIdx.y, qb = blockIdx.x * 64;
  const int kvh = h >> 2;
  const int t = threadIdx.x, lane = t & 63, w = t >> 6;
  const int fr = lane & 15, fq = lane >> 4;

  __shared__ u16 Kl[64][136];       // keys x d (padded: 272B row stride)
  __shared__ u16 Vl[128][72];       // d x keys (padded: 144B row stride)
  __shared__ u16 Pl[4][16][72];     // per-wave P tile
  __shared__ float ml[64];

  // Q fragments: A-operand row m = fr -> q row qb + w*16 + fr
  bf16x8 qf[4];
  {
    const int qrow = qb + w * 16 + fr;
    const long qbase = (((long)b * SS + qrow) * NH + h) * HD;
#pragma unroll
    for (int kk = 0; kk < 4; kk++)
      qf[kk] = *(const bf16x8*)&Q[qbase + kk * 32 + fq * 8];
  }

  f32x4 oacc[8] = {};
  float mrow[4], lrow[4];
#pragma unroll
  for (int j = 0; j < 4; j++) { mrow[j] = -1e30f; lrow[j] = 0.f; }

  const int ntiles = qb / 64 + 1;
  for (int kvt = 0; kvt < ntiles; kvt++) {
    const int kv0 = kvt * 64;
    // ---- stage K tile [64][128] and Vt tile [128][64] ----
    {
      const int key = t >> 4, dc = (t & 15) * 8;
#pragma unroll
      for (int i = 0; i < 4; i++) {
        long g = (((long)b * SS + kv0 + key + i * 16) * NKV + kvh) * HD + dc;
        *(bf16x8*)&Kl[key + i * 16][dc] = *(const bf16x8*)&K[g];
      }
      const int d = t >> 3, kc = (t & 7) * 8;
#pragma unroll
      for (int i = 0; i < 4; i++) {
        long g = (((long)b * NKV + kvh) * HD + d + i * 32) * SS + kv0 + kc;
        *(bf16x8*)&Vl[d + i * 32][kc] = *(const bf16x8*)&Vt[g];
      }
      if (t < 64) ml[t] = amask[b * SS + kv0 + t];
    }
    __syncthreads();

    // ---- S = Q K^T ----
    f32x4 sacc[4] = {};
#pragma unroll
    for (int n = 0; n < 4; n++)
#pragma unroll
      for (int kk = 0; kk < 4; kk++) {
        bf16x8 kf = *(const bf16x8*)&Kl[n * 16 + fr][kk * 32 + fq * 8];
        sacc[n] = __builtin_amdgcn_mfma_f32_16x16x32_bf16(qf[kk], kf, sacc[n], 0, 0, 0);
      }

    // ---- scale + mask ----
    const float scale = 0.08838834764831845f;   // 1/sqrt(128)
    const bool diag = (kv0 + 63 >= qb);
    float sv[4][4];
#pragma unroll
    for (int n = 0; n < 4; n++) {
      const int key = kv0 + n * 16 + fr;
      const float mk = ml[n * 16 + fr];
#pragma unroll
      for (int j = 0; j < 4; j++) {
        float v = sacc[n][j] * scale;
        int qr = qb + w * 16 + fq * 4 + j;
        if ((diag && key > qr) || mk <= 0.f) v = -1e30f;
        sv[n][j] = v;
      }
    }

    // ---- online softmax (rows live across 16-lane groups) ----
    float p[4][4], alpha[4];
#pragma unroll
    for (int j = 0; j < 4; j++) {
      float mx = fmaxf(fmaxf(sv[0][j], sv[1][j]), fmaxf(sv[2][j], sv[3][j]));
#pragma unroll
      for (int d = 1; d < 16; d <<= 1) mx = fmaxf(mx, __shfl_xor(mx, d, 64));
      float mnew = fmaxf(mrow[j], mx);
      alpha[j] = exp2f((mrow[j] - mnew) * 1.4426950408889634f);
      float sum = 0.f;
#pragma unroll
      for (int n = 0; n < 4; n++) {
        float pv = exp2f((sv[n][j] - mnew) * 1.4426950408889634f);
        p[n][j] = pv;
        sum += pv;
      }
#pragma unroll
      for (int d = 1; d < 16; d <<= 1) sum += __shfl_xor(sum, d, 64);
      lrow[j] = lrow[j] * alpha[j] + sum;
      mrow[j] = mnew;
    }

    // rescale O
#pragma unroll
    for (int no = 0; no < 8; no++)
#pragma unroll
      for (int j = 0; j < 4; j++) oacc[no][j] *= alpha[j];

    // P -> LDS (per-wave region)
#pragma unroll
    for (int n = 0; n < 4; n++)
#pragma unroll
      for (int j = 0; j < 4; j++)
        Pl[w][fq * 4 + j][n * 16 + fr] = f2bf(p[n][j]);

    // ---- O += P V ----
#pragma unroll
    for (int kk = 0; kk < 2; kk++) {
      bf16x8 pf = *(const bf16x8*)&Pl[w][fr][kk * 32 + fq * 8];
#pragma unroll
      for (int no = 0; no < 8; no++) {
        bf16x8 vf = *(const bf16x8*)&Vl[no * 16 + fr][kk * 32 + fq * 8];
        oacc[no] = __builtin_amdgcn_mfma_f32_16x16x32_bf16(pf, vf, oacc[no], 0, 0, 0);
      }
    }
    __syncthreads();
  }

  // ---- epilogue ----
#pragma unroll
  for (int j = 0; j < 4; j++) {
    const int row = qb + w * 16 + fq * 4 + j;
    const float inv = 1.0f / lrow[j];
    const long obase = (((long)b * SS + row) * NH + h) * HD;
#pragma unroll
    for (int no = 0; no < 8; no++)
      O[obase + no * 16 + fr] = f2bf(oacc[no][j] * inv);
  }
}

// ---------------- launch ----------------

extern "C" void kernel_launch(void* const* d_in, const int* in_sizes, int n_in,
                              void* d_out, int out_size, void* d_ws, size_t ws_size,
                              hipStream_t stream) {
  const float* hs    = (const float*)d_in[0];
  const float* amask = (const float*)d_in[1];
  const int*   pid   = (const int*)d_in[2];
  const float* Wq    = (const float*)d_in[3];
  const float* Wk    = (const float*)d_in[4];
  const float* Wv    = (const float*)d_in[5];
  const float* Wo    = (const float*)d_in[6];
  float* out = (float*)d_out;

  char* ws = (char*)d_ws;
  const size_t MB = 1024ull * 1024ull;
  u16* Xb   = (u16*)(ws + 0);         // 32MB, later reused as attention output
  u16* Wqt  = (u16*)(ws + 32 * MB);   // 32MB
  u16* Wkt  = (u16*)(ws + 64 * MB);   // 8MB
  u16* Wvt  = (u16*)(ws + 72 * MB);   // 8MB
  u16* Wot  = (u16*)(ws + 80 * MB);   // 32MB
  u16* Qb   = (u16*)(ws + 112 * MB);  // 32MB
  u16* Kb   = (u16*)(ws + 144 * MB);  // 8MB
  u16* Vb   = (u16*)(ws + 152 * MB);  // 8MB
  u16* Vtb  = (u16*)(ws + 160 * MB);  // 8MB
  float* st = (float*)(ws + 168 * MB);// 1MB
  float* ct = (float*)(ws + 169 * MB);// 1MB
  u16* Ab = Xb;                       // alias: Xb dead after QKV GEMMs

  rope_table<<<(MAXPOS * 64) / 256, 256, 0, stream>>>(st, ct);
  conv_bf16<<<(TOK * HIDDEN / 8) / 256, 256, 0, stream>>>(hs, Xb, TOK * HIDDEN / 8);
  conv_transpose<<<dim3(HIDDEN / 64, HIDDEN / 64), 256, 0, stream>>>(Wq, Wqt, HIDDEN, HIDDEN);
  conv_transpose<<<dim3(1024 / 64, HIDDEN / 64), 256, 0, stream>>>(Wk, Wkt, HIDDEN, 1024);
  conv_transpose<<<dim3(1024 / 64, HIDDEN / 64), 256, 0, stream>>>(Wv, Wvt, HIDDEN, 1024);
  conv_transpose<<<dim3(HIDDEN / 64, HIDDEN / 64), 256, 0, stream>>>(Wo, Wot, HIDDEN, HIDDEN);

  gemm_bt<u16><<<dim3(HIDDEN / 128, TOK / 128), 256, 0, stream>>>(Xb, Wqt, Qb, TOK, HIDDEN, HIDDEN);
  gemm_bt<u16><<<dim3(1024 / 128, TOK / 128), 256, 0, stream>>>(Xb, Wkt, Kb, TOK, 1024, HIDDEN);
  gemm_bt<u16><<<dim3(1024 / 128, TOK / 128), 256, 0, stream>>>(Xb, Wvt, Vb, TOK, 1024, HIDDEN);

  rope_apply<<<(TOK * NH * 64) / 256, 256, 0, stream>>>(Qb, pid, st, ct, NH, TOK * NH * 64);
  rope_apply<<<(TOK * NKV * 64) / 256, 256, 0, stream>>>(Kb, pid, st, ct, NKV, TOK * NKV * 64);

  vtrans<<<dim3(SS / 64, HD / 64, BB * NKV), 256, 0, stream>>>(Vb, Vtb);

  attn_fwd<<<dim3(SS / 64, NH, BB), 256, 0, stream>>>(Qb, Kb, Vtb, amask, Ab);

  gemm_bt<float><<<dim3(HIDDEN / 128, TOK / 128), 256, 0, stream>>>(Ab, Wot, out, TOK, HIDDEN, HIDDEN);
}